// Round 3
// baseline (111.095 us; speedup 1.0000x reference)
//
#include <hip/hip_runtime.h>
#include <math.h>

#define DIM 1184         // 256 + 384 + 320 + 224
#define NV4 296          // DIM / 4
// chunk boundaries in float4 units: [0,64) c0, [64,160) c1, [160,240) c2, [240,296) c3

typedef __attribute__((ext_vector_type(4))) float f32x4;

__global__ __launch_bounds__(256) void normact_kernel(const float* __restrict__ x,
                                                      float* __restrict__ out,
                                                      int rows) {
    const int wave = threadIdx.x >> 6;
    const int lane = threadIdx.x & 63;
    const int rstride = gridDim.x * 4;

    for (int row = blockIdx.x * 4 + wave; row < rows; row += rstride) {
        const f32x4* __restrict__ xin = (const f32x4*)(x  + (size_t)row * DIM);
        f32x4* __restrict__ xo        = (f32x4*)(out + (size_t)row * DIM);

        f32x4 v[5];
        float s[4] = {0.f, 0.f, 0.f, 0.f};

        #pragma unroll
        for (int k = 0; k < 5; ++k) {
            int idx = lane + k * 64;
            if (idx < NV4) {
                f32x4 t = __builtin_nontemporal_load(xin + idx);
                v[k] = t;
                int c = (idx < 64) ? 0 : (idx < 160) ? 1 : (idx < 240) ? 2 : 3;
                s[c] += t.x * t.x + t.y * t.y + t.z * t.z + t.w * t.w;
            }
        }

        // 64-lane butterfly reduction of the 4 per-chunk partial sums
        #pragma unroll
        for (int m = 1; m < 64; m <<= 1) {
            #pragma unroll
            for (int c = 0; c < 4; ++c)
                s[c] += __shfl_xor(s[c], m, 64);
        }

        // per-chunk scalars: n = sqrt(mean(x^2)); scal = act(n)
        const float wrec0 = 1.f / 256.f, wrec1 = 1.f / 384.f,
                    wrec2 = 1.f / 320.f, wrec3 = 1.f / 224.f;
        float scal[4];
        {
            float n2, n;
            n2 = s[0] * wrec0; n = (n2 > 0.f) ? sqrtf(n2) : 1.f;
            scal[0] = n / (1.f + __expf(-n));          // silu
            n2 = s[1] * wrec1; n = (n2 > 0.f) ? sqrtf(n2) : 1.f;
            scal[1] = 1.f / (1.f + __expf(-n));        // sigmoid
            n2 = s[2] * wrec2; n = (n2 > 0.f) ? sqrtf(n2) : 1.f;
            scal[2] = tanhf(n);                        // tanh
            n2 = s[3] * wrec3; n = (n2 > 0.f) ? sqrtf(n2) : 1.f;
            scal[3] = n / (1.f + __expf(-n));          // silu
        }

        #pragma unroll
        for (int k = 0; k < 5; ++k) {
            int idx = lane + k * 64;
            if (idx < NV4) {
                int c = (idx < 64) ? 0 : (idx < 160) ? 1 : (idx < 240) ? 2 : 3;
                float f = scal[c];
                f32x4 t = v[k];
                t.x *= f; t.y *= f; t.z *= f; t.w *= f;
                __builtin_nontemporal_store(t, xo + idx);
            }
        }
    }
}

extern "C" void kernel_launch(void* const* d_in, const int* in_sizes, int n_in,
                              void* d_out, int out_size, void* d_ws, size_t ws_size,
                              hipStream_t stream) {
    const float* x = (const float*)d_in[0];
    float* out = (float*)d_out;
    int rows = in_sizes[0] / DIM;   // 65536
    int vblocks = (rows + 3) / 4;   // 16384 virtual blocks
    int grid = vblocks < 2048 ? vblocks : 2048;  // persistent blocks, grid-stride
    normact_kernel<<<grid, 256, 0, stream>>>(x, out, rows);
}

// Round 4
// 110.214 us; speedup vs baseline: 1.0080x; 1.0080x over previous
//
#include <hip/hip_runtime.h>
#include <math.h>

#define DIM 1184         // 256 + 384 + 320 + 224
#define NV4 296          // DIM / 4
// chunk boundaries in float4 units: [0,64) c0, [64,160) c1, [160,240) c2, [240,296) c3

typedef __attribute__((ext_vector_type(4))) float f32x4;

__device__ __forceinline__ float chunk_scale(int c, float sum) {
    // n = sqrt(mean(x^2)); act(n)
    const float wrec[4] = {1.f / 256.f, 1.f / 384.f, 1.f / 320.f, 1.f / 224.f};
    float n2 = sum * wrec[c];
    float n = (n2 > 0.f) ? sqrtf(n2) : 1.f;
    float sg = 1.f / (1.f + __expf(-n));
    if (c == 0 || c == 3) return n * sg;   // silu
    if (c == 1) return sg;                 // sigmoid
    return tanhf(n);                       // tanh
}

__global__ __launch_bounds__(256) void normact_kernel(const float* __restrict__ x,
                                                      float* __restrict__ out,
                                                      int rows) {
    const int wave = threadIdx.x >> 6;
    const int lane = threadIdx.x & 63;
    // each wave owns 2 consecutive rows; block of 4 waves owns 8 rows
    const int rowA = blockIdx.x * 8 + wave * 2;
    const int rowB = rowA + 1;
    if (rowA >= rows) return;   // wave-uniform

    const f32x4* __restrict__ xa = (const f32x4*)(x  + (size_t)rowA * DIM);
    const f32x4* __restrict__ xb = (const f32x4*)(x  + (size_t)rowB * DIM);
    f32x4* __restrict__ oa       = (f32x4*)(out + (size_t)rowA * DIM);
    f32x4* __restrict__ ob       = (f32x4*)(out + (size_t)rowB * DIM);

    f32x4 va[5], vb[5];
    float sa[4] = {0.f, 0.f, 0.f, 0.f};
    float sb[4] = {0.f, 0.f, 0.f, 0.f};

    // issue ALL loads for both rows first (max MLP), then consume
    #pragma unroll
    for (int k = 0; k < 5; ++k) {
        int idx = lane + k * 64;
        if (idx < NV4) {
            va[k] = __builtin_nontemporal_load(xa + idx);
            vb[k] = __builtin_nontemporal_load(xb + idx);
        }
    }

    #pragma unroll
    for (int k = 0; k < 5; ++k) {
        int idx = lane + k * 64;
        if (idx < NV4) {
            int c = (idx < 64) ? 0 : (idx < 160) ? 1 : (idx < 240) ? 2 : 3;
            f32x4 ta = va[k], tb = vb[k];
            sa[c] += ta.x * ta.x + ta.y * ta.y + ta.z * ta.z + ta.w * ta.w;
            sb[c] += tb.x * tb.x + tb.y * tb.y + tb.z * tb.z + tb.w * tb.w;
        }
    }

    // 64-lane butterfly reduction, both rows together
    #pragma unroll
    for (int m = 1; m < 64; m <<= 1) {
        #pragma unroll
        for (int c = 0; c < 4; ++c) {
            sa[c] += __shfl_xor(sa[c], m, 64);
            sb[c] += __shfl_xor(sb[c], m, 64);
        }
    }

    float scalA[4], scalB[4];
    #pragma unroll
    for (int c = 0; c < 4; ++c) {
        scalA[c] = chunk_scale(c, sa[c]);
        scalB[c] = chunk_scale(c, sb[c]);
    }

    #pragma unroll
    for (int k = 0; k < 5; ++k) {
        int idx = lane + k * 64;
        if (idx < NV4) {
            int c = (idx < 64) ? 0 : (idx < 160) ? 1 : (idx < 240) ? 2 : 3;
            float fa = scalA[c], fb = scalB[c];
            f32x4 ta = va[k], tb = vb[k];
            ta.x *= fa; ta.y *= fa; ta.z *= fa; ta.w *= fa;
            tb.x *= fb; tb.y *= fb; tb.z *= fb; tb.w *= fb;
            __builtin_nontemporal_store(ta, oa + idx);
            __builtin_nontemporal_store(tb, ob + idx);
        }
    }
}

extern "C" void kernel_launch(void* const* d_in, const int* in_sizes, int n_in,
                              void* d_out, int out_size, void* d_ws, size_t ws_size,
                              hipStream_t stream) {
    const float* x = (const float*)d_in[0];
    float* out = (float*)d_out;
    int rows = in_sizes[0] / DIM;      // 65536 (even)
    int grid = (rows + 7) / 8;         // 8192 one-shot blocks, 2 rows/wave
    normact_kernel<<<grid, 256, 0, stream>>>(x, out, rows);
}

// Round 5
// 104.779 us; speedup vs baseline: 1.0603x; 1.0519x over previous
//
#include <hip/hip_runtime.h>
#include <math.h>

#define DIM 1184         // 256 + 384 + 320 + 224
#define NV4 296          // DIM / 4
// chunk boundaries in float4 units: [0,64) c0, [64,160) c1, [160,240) c2, [240,296) c3

typedef __attribute__((ext_vector_type(4))) float f32x4;

// Best measured config (R1): one-shot blocks, 1 row/wave, nt load/store.
// - nt hints: +12% (cache-path bypass; input/output are stream-once, 620MB >> L3)
// - grid-stride persistent blocks: REGRESSED (serializes cross-row deps in-register)
// - 2 rows/wave straight-line: REGRESSED (VGPR step 8->4 waves/SIMD)
// At 8 waves/SIMD, TLP provides the latency hiding; keep VGPR < 64.

__global__ __launch_bounds__(256) void normact_kernel(const float* __restrict__ x,
                                                      float* __restrict__ out,
                                                      int rows) {
    const int wave = threadIdx.x >> 6;
    const int lane = threadIdx.x & 63;
    const int row  = blockIdx.x * 4 + wave;
    if (row >= rows) return;   // wave-uniform guard

    const f32x4* __restrict__ xin = (const f32x4*)(x  + (size_t)row * DIM);
    f32x4* __restrict__ xo        = (f32x4*)(out + (size_t)row * DIM);

    f32x4 v[5];
    float s[4] = {0.f, 0.f, 0.f, 0.f};

    #pragma unroll
    for (int k = 0; k < 5; ++k) {
        int idx = lane + k * 64;
        if (idx < NV4) {
            f32x4 t = __builtin_nontemporal_load(xin + idx);
            v[k] = t;
            int c = (idx < 64) ? 0 : (idx < 160) ? 1 : (idx < 240) ? 2 : 3;
            s[c] += t.x * t.x + t.y * t.y + t.z * t.z + t.w * t.w;
        }
    }

    // 64-lane butterfly reduction of the 4 per-chunk partial sums
    #pragma unroll
    for (int m = 1; m < 64; m <<= 1) {
        #pragma unroll
        for (int c = 0; c < 4; ++c)
            s[c] += __shfl_xor(s[c], m, 64);
    }

    // per-chunk scalars: n = sqrt(mean(x^2)); scal = act(n)
    const float wrec0 = 1.f / 256.f, wrec1 = 1.f / 384.f,
                wrec2 = 1.f / 320.f, wrec3 = 1.f / 224.f;
    float scal[4];
    {
        float n2, n;
        n2 = s[0] * wrec0; n = (n2 > 0.f) ? sqrtf(n2) : 1.f;
        scal[0] = n / (1.f + __expf(-n));          // silu
        n2 = s[1] * wrec1; n = (n2 > 0.f) ? sqrtf(n2) : 1.f;
        scal[1] = 1.f / (1.f + __expf(-n));        // sigmoid
        n2 = s[2] * wrec2; n = (n2 > 0.f) ? sqrtf(n2) : 1.f;
        scal[2] = tanhf(n);                        // tanh
        n2 = s[3] * wrec3; n = (n2 > 0.f) ? sqrtf(n2) : 1.f;
        scal[3] = n / (1.f + __expf(-n));          // silu
    }

    #pragma unroll
    for (int k = 0; k < 5; ++k) {
        int idx = lane + k * 64;
        if (idx < NV4) {
            int c = (idx < 64) ? 0 : (idx < 160) ? 1 : (idx < 240) ? 2 : 3;
            float f = scal[c];
            f32x4 t = v[k];
            t.x *= f; t.y *= f; t.z *= f; t.w *= f;
            __builtin_nontemporal_store(t, xo + idx);
        }
    }
}

extern "C" void kernel_launch(void* const* d_in, const int* in_sizes, int n_in,
                              void* d_out, int out_size, void* d_ws, size_t ws_size,
                              hipStream_t stream) {
    const float* x = (const float*)d_in[0];
    float* out = (float*)d_out;
    int rows = in_sizes[0] / DIM;
    int grid = (rows + 3) / 4;
    normact_kernel<<<grid, 256, 0, stream>>>(x, out, rows);
}